// Round 18
// baseline (73.982 us; speedup 1.0000x reference)
//
#include <hip/hip_runtime.h>

namespace {

constexpr int kB  = 16;    // batches
constexpr int kP  = 8;     // pieces
constexpr int kNT = 512;   // time steps (incl. t=0)
constexpr int kNX = 2048;  // cells
constexpr int kW  = 32;    // steps per super-step
constexpr int kChunk = 64;                // cells owned per wave
constexpr int kNS = 16;                   // super-steps: 15*32 + 31 = 511 rows
constexpr int kSolver = 512;              // 16 batches x 32 chunks
// region per wave = kChunk + 2*kW = 128 cells = 64 lanes x 2 cells

// d_ws layout
constexpr size_t kFlagsBytes = (size_t)kSolver * kNS * 4;   // 32 KB
constexpr size_t kHaloOff    = 65536;  // int halo[512][kNS][kChunk]; slot s=0 of
                                       // each block is never read -> per-block
                                       // dump target for non-writer lanes.

// Cross-lane shift by one lane via DPP (VALU; no LDS round-trip).
__device__ __forceinline__ float dpp_shr1(float x) {
    return __builtin_bit_cast(float,
        __builtin_amdgcn_update_dpp(0, __builtin_bit_cast(int, x), 0x138, 0xF, 0xF, true));
}
__device__ __forceinline__ float dpp_shl1(float x) {
    return __builtin_bit_cast(float,
        __builtin_amdgcn_update_dpp(0, __builtin_bit_cast(int, x), 0x130, 0xF, 0xF, true));
}

// m = max(-xL, xR, 0) in ONE VOP3 (neg modifier free). Godunov flux for
// f(u)=u(1-u) in x=u-1/2 space: F = 1/4 - m^2; the 1/4 cancels in the flux
// difference, so the update is x += lam*(G_r - G_l), G = m^2.
__device__ __forceinline__ float max3n(float xL, float xR) {
    float m;
    asm("v_max3_f32 %0, -%1, %2, 0" : "=v"(m) : "v"(xL), "v"(xR));
    return m;
}

// Agent-scope coherence-point ops (relaxed: no cache maintenance).
__device__ __forceinline__ void mall_store(int* p, float v) {
    (void)__hip_atomic_exchange(p, __builtin_bit_cast(int, v),
                                __ATOMIC_RELAXED, __HIP_MEMORY_SCOPE_AGENT);
}
__device__ __forceinline__ float mall_loadf(const int* p) {
    return __builtin_bit_cast(float,
        __hip_atomic_load(p, __ATOMIC_RELAXED, __HIP_MEMORY_SCOPE_AGENT));
}
__device__ __forceinline__ int mall_loadi(const int* p) {
    return __hip_atomic_load(p, __ATOMIC_RELAXED, __HIP_MEMORY_SCOPE_AGENT);
}

__global__ __launch_bounds__(64)
void godunov_fused(const float* __restrict__ xs,   // (B, P+1)
                   const float* __restrict__ ks,   // (B, P)
                   const int*   __restrict__ pm,   // (B, P)
                   const float* __restrict__ dxp,  // (B,)
                   const float* __restrict__ dtp,  // (B,)
                   float* __restrict__ out,        // (B,1,NT,NX) fp32
                   int*   __restrict__ flags,      // [512][kNS], pre-zeroed
                   int*   __restrict__ halo)       // [512][kNS][kChunk] f32 bits
{
    const int p    = blockIdx.x;
    const int b    = p >> 5;         // batch
    const int k    = p & 31;         // chunk within batch
    const int lane = threadIdx.x;    // 0..63, one wave per block
    const int rs   = k * kChunk - kW;    // region start (may be <0)
    const int gi0  = rs + 2 * lane;      // this lane's first cell

    const float dxv = dxp[0];
    const float lam = dtp[0] / dxv;

    // ---- piecewise-constant IC parameters ----
    int np = 0;
    float bnds[kP];
#pragma unroll
    for (int j = 0; j < kP; ++j) {
        int m = pm[b * kP + j];
        np += m;
        bnds[j] = m ? xs[b * (kP + 1) + j + 1] : __builtin_inff();
    }
    const int cap = np - 1;

    auto icval = [&](int gi) -> float {
        float xc = ((float)gi + 0.5f) * dxv;
        int idx = 0;
#pragma unroll
        for (int j = 0; j < kP; ++j) idx += (xc >= bnds[j]) ? 1 : 0;
        idx = min(idx, cap);
        return ks[b * kP + idx];
    };

    // Constant ghost values (reference: frozen IC endpoints).
    const float gL = icval(0);
    const float gR = icval(kNX - 1);

    // Region is 2-aligned; each lane's 2 cells are all-in or all-out of domain.
    const bool  laneIn  = (gi0 >= 0) && (gi0 < kNX);
    const float gvv     = (gi0 < 0) ? gL : gR;
    const float gxv     = gvv - 0.5f;              // pinned value in x-space
    const bool  edgeBlk = (k == 0) || (k == 31);   // only these ever pin

    // ---- seed at t=0 from IC (state in x = u - 1/2 space) ----
    float x0 = (laneIn ? icval(gi0)     : gvv) - 0.5f;
    float x1 = (laneIn ? icval(gi0 + 1) : gvv) - 0.5f;

    // Lanes 16..47 own exactly the chunk (cells k*64 .. k*64+63).
    const bool writer = (lane >= 16) && (lane < 48);

    if (writer) {   // row 0 = IC (off the hot loop)
        float* p0 = out + ((size_t)b * kNT) * kNX;
        *reinterpret_cast<float2*>(p0 + gi0) = make_float2(x0 + 0.5f, x1 + 0.5f);
    }

    // Unconditional per-step store: writer lanes walk the output rows; the
    // other 32 lanes hit a per-block dump (halo slot s=0, never read, 32x8B)
    // with increment 0. No exec-mask branch in the hot loop.
    const int dumpIdx = (lane < 16) ? lane : (lane - 32);   // 0..31
    float* pstore = writer
        ? out + ((size_t)b * kNT + 1) * kNX + gi0
        : reinterpret_cast<float*>(halo + (size_t)p * kNS * kChunk) + 2 * dumpIdx;
    const size_t incB = writer ? (size_t)kNX * sizeof(float) : 0;

    const int fbase = p * kNS;

    // Per step: 2 DPP + 2 max3 + 2 mul + 2 sub + 2 fma (+2 cndmask edge-only)
    auto do_step = [&]() {
        float xm = dpp_shr1(x1);      // x of cell gi0-1
        float m0 = max3n(xm, x0);     // face left of cell0
        float m1 = max3n(x0, x1);     // face cell0|cell1
        float G0 = m0 * m0, G1 = m1 * m1;
        float G2 = dpp_shl1(G0);      // right lane's G0 = right face of cell1
        x0 = __builtin_fmaf(lam, G1 - G0, x0);
        x1 = __builtin_fmaf(lam, G2 - G1, x1);
        if (edgeBlk) {   // wave-uniform; skipped by 30/32 blocks
            x0 = laneIn ? x0 : gxv;
            x1 = laneIn ? x1 : gxv;
        }
    };

    auto step_store = [&]() {
        do_step();
        *reinterpret_cast<float2*>(pstore) = make_float2(x0 + 0.5f, x1 + 0.5f);
        pstore = reinterpret_cast<float*>(reinterpret_cast<char*>(pstore) + incB);
    };

#pragma unroll 1
    for (int s = 0; s < kNS; ++s) {
        // ---- re-seed halo lanes from neighbors (state at time 32*s) ----
        if (s > 0) {
            const bool needL = (k > 0), needR = (k < 31);
            if (lane == 0) {   // lane-0-only poll; whole wave waits on branch
                const int* fL = flags + (p - 1) * kNS + s;
                const int* fR = flags + (p + 1) * kNS + s;
                int okL = needL ? 0 : 1, okR = needR ? 0 : 1;
                for (int it = 0; it < (1 << 22); ++it) {
                    if (!okL) okL = mall_loadi(fL);
                    if (!okR) okR = mall_loadi(fR);
                    if (okL && okR) break;
                    __builtin_amdgcn_s_sleep(1);
                }
            }
            asm volatile("" ::: "memory");   // keep data reads below the spin

            if (lane < 16) {
                if (needL) {  // left neighbor's cells 32..63 (their halo[32..])
                    const int* hp = halo + ((size_t)((p - 1) * kNS + s)) * kChunk
                                  + 32 + 2 * lane;
                    x0 = mall_loadf(hp)     - 0.5f;
                    x1 = mall_loadf(hp + 1) - 0.5f;
                }  // k==0: lanes stay pinned
            } else if (lane >= 48) {
                if (needR) {  // right neighbor's cells 0..31
                    const int* hp = halo + ((size_t)((p + 1) * kNS + s)) * kChunk
                                  + 2 * (lane - 48);
                    x0 = mall_loadf(hp)     - 0.5f;
                    x1 = mall_loadf(hp + 1) - 0.5f;
                }  // k==31: lanes stay pinned
            }
            // lanes 16..47 keep their registers (own chunk, still valid)
        }

        // ---- steps: 4 octets (last superstep: 3 octets + 7) ----
        const int noct = (s == kNS - 1) ? 3 : 4;
#pragma unroll 1
        for (int g = 0; g < noct; ++g) {
#pragma unroll
            for (int q = 0; q < 8; ++q) step_store();
        }
        if (s == kNS - 1) {
#pragma unroll
            for (int q = 0; q < 7; ++q) step_store();   // rows 505..511
        }

        // ---- publish own chunk state (time 32*(s+1)) + flag, all relaxed ----
        if (s < kNS - 1) {
            if (writer) {
                int* hp = halo + ((size_t)(fbase + (s + 1))) * kChunk + 2 * (lane - 16);
                mall_store(hp,     x0 + 0.5f);
                mall_store(hp + 1, x1 + 0.5f);
            }
            // drain data exchs (vmcnt covers global atomics), then set flag
            asm volatile("s_waitcnt vmcnt(0)" ::: "memory");
            if (lane == 0)
                (void)__hip_atomic_exchange(flags + fbase + (s + 1), 1,
                                            __ATOMIC_RELAXED, __HIP_MEMORY_SCOPE_AGENT);
        }
    }
}

}  // namespace

extern "C" void kernel_launch(void* const* d_in, const int* in_sizes, int n_in,
                              void* d_out, int out_size, void* d_ws, size_t ws_size,
                              hipStream_t stream) {
    const float* xs  = (const float*)d_in[0];
    const float* ks  = (const float*)d_in[1];
    const int*   pm  = (const int*)d_in[2];
    const float* dxv = (const float*)d_in[3];
    const float* dtv = (const float*)d_in[4];
    // d_in[5] = t_coords: only carries the (NT, NX) shape; values unused.
    float* out = (float*)d_out;

    int* flags = (int*)d_ws;
    int* halo  = (int*)((char*)d_ws + kHaloOff);

    // Flags must be zeroed every call (d_ws is not re-poisoned between replays).
    hipMemsetAsync(flags, 0, kFlagsBytes, stream);

    hipLaunchKernelGGL(godunov_fused, dim3(kSolver), dim3(64), 0, stream,
                       xs, ks, pm, dxv, dtv, out, flags, halo);
}

// Round 19
// 69.443 us; speedup vs baseline: 1.0654x; 1.0654x over previous
//
#include <hip/hip_runtime.h>

namespace {

constexpr int kB  = 16;    // batches
constexpr int kP  = 8;     // pieces
constexpr int kNT = 512;   // time steps (incl. t=0)
constexpr int kNX = 2048;  // cells
constexpr int kW  = 64;    // steps per super-step
constexpr int kChunk = 128;               // cells owned per wave
constexpr int kNS = 8;                    // super-steps: 7*64 + 63 = 511 rows
constexpr int kSolver = 256;              // 16 batches x 16 chunks

// d_ws layout
constexpr size_t kFlagsBytes = (size_t)kSolver * kNS * 4;   // 8 KB
constexpr size_t kHaloOff    = 32768;  // int halo[256][kNS][kChunk]; slot s=0 of
                                       // each block is never read -> per-block
                                       // dump target for non-writer lanes.

// Cross-lane shift by one lane via DPP (VALU; no LDS round-trip).
__device__ __forceinline__ float dpp_shr1(float x) {
    return __builtin_bit_cast(float,
        __builtin_amdgcn_update_dpp(0, __builtin_bit_cast(int, x), 0x138, 0xF, 0xF, true));
}
__device__ __forceinline__ float dpp_shl1(float x) {
    return __builtin_bit_cast(float,
        __builtin_amdgcn_update_dpp(0, __builtin_bit_cast(int, x), 0x130, 0xF, 0xF, true));
}

// m = max(-xL, xR, 0) in ONE VOP3 (neg modifier free). Godunov flux for
// f(u)=u(1-u) in x=u-1/2 space: F = 1/4 - m^2; the 1/4 cancels in the flux
// difference, so the update is x += lam*(G_r - G_l), G = m^2.
__device__ __forceinline__ float max3n(float xL, float xR) {
    float m;
    asm("v_max3_f32 %0, -%1, %2, 0" : "=v"(m) : "v"(xL), "v"(xR));
    return m;
}

// Agent-scope coherence-point ops (relaxed: no cache maintenance).
__device__ __forceinline__ void mall_store(int* p, float v) {
    (void)__hip_atomic_exchange(p, __builtin_bit_cast(int, v),
                                __ATOMIC_RELAXED, __HIP_MEMORY_SCOPE_AGENT);
}
__device__ __forceinline__ float mall_loadf(const int* p) {
    return __builtin_bit_cast(float,
        __hip_atomic_load(p, __ATOMIC_RELAXED, __HIP_MEMORY_SCOPE_AGENT));
}
__device__ __forceinline__ int mall_loadi(const int* p) {
    return __hip_atomic_load(p, __ATOMIC_RELAXED, __HIP_MEMORY_SCOPE_AGENT);
}

__global__ __launch_bounds__(64)
void godunov_fused(const float* __restrict__ xs,   // (B, P+1)
                   const float* __restrict__ ks,   // (B, P)
                   const int*   __restrict__ pm,   // (B, P)
                   const float* __restrict__ dxp,  // (B,)
                   const float* __restrict__ dtp,  // (B,)
                   float* __restrict__ out,        // (B,1,NT,NX) fp32
                   int*   __restrict__ flags,      // [256][kNS], pre-zeroed
                   int*   __restrict__ halo)       // [256][kNS][kChunk] f32 bits
{
    const int p    = blockIdx.x;
    const int b    = p >> 4;         // batch
    const int k    = p & 15;         // chunk within batch
    const int lane = threadIdx.x;    // 0..63, one wave per block
    const int rs   = k * kChunk - kW;    // region start (may be <0)
    const int gi0  = rs + 4 * lane;      // this lane's first cell

    const float dxv = dxp[0];
    const float lam = dtp[0] / dxv;

    // ---- piecewise-constant IC parameters ----
    int np = 0;
    float bnds[kP];
#pragma unroll
    for (int j = 0; j < kP; ++j) {
        int m = pm[b * kP + j];
        np += m;
        bnds[j] = m ? xs[b * (kP + 1) + j + 1] : __builtin_inff();
    }
    const int cap = np - 1;

    auto icval = [&](int gi) -> float {
        float xc = ((float)gi + 0.5f) * dxv;
        int idx = 0;
#pragma unroll
        for (int j = 0; j < kP; ++j) idx += (xc >= bnds[j]) ? 1 : 0;
        idx = min(idx, cap);
        return ks[b * kP + idx];
    };

    // Constant ghost values (reference: frozen IC endpoints).
    const float gL = icval(0);
    const float gR = icval(kNX - 1);

    // Region is 4-aligned; each lane's 4 cells are all-in or all-out of domain.
    const bool  laneIn  = (gi0 >= 0) && (gi0 < kNX);
    const float gvv     = (gi0 < 0) ? gL : gR;
    const float gxv     = gvv - 0.5f;              // pinned value in x-space
    const bool  edgeBlk = (k == 0) || (k == 15);   // only these ever pin

    // ---- seed at t=0 from IC (state in x = u - 1/2 space) ----
    float x[4];
#pragma unroll
    for (int c = 0; c < 4; ++c)
        x[c] = (laneIn ? icval(gi0 + c) : gvv) - 0.5f;

    // Lanes 16..47 own exactly the chunk (cells k*128 .. k*128+127).
    const bool writer = (lane >= 16) && (lane < 48);

    if (writer) {   // row 0 = IC (off the hot loop)
        float* p0 = out + ((size_t)b * kNT) * kNX;
        *reinterpret_cast<float4*>(p0 + gi0) =
            make_float4(x[0] + 0.5f, x[1] + 0.5f, x[2] + 0.5f, x[3] + 0.5f);
    }

    // Unconditional stores: writer lanes walk output rows; other 32 lanes hit
    // a per-block dump (halo slot s=0, never read) with increment 0.
    const int dumpIdx = (lane < 16) ? lane : (lane - 32);   // 0..31
    char* pstore = writer
        ? (char*)(out + ((size_t)b * kNT + 1) * kNX + gi0)
        : (char*)(reinterpret_cast<float*>(halo + (size_t)p * kNS * kChunk) + 4 * dumpIdx);
    const size_t incB = writer ? (size_t)kNX * sizeof(float) : 0;

    const int fbase = p * kNS;

    auto do_step = [&]() {
        float xm = dpp_shr1(x[3]);    // x of cell gi0-1
        float xp = dpp_shl1(x[0]);    // x of cell gi0+4
        float m0 = max3n(xm,   x[0]);
        float m1 = max3n(x[0], x[1]);
        float m2 = max3n(x[1], x[2]);
        float m3 = max3n(x[2], x[3]);
        float m4 = max3n(x[3], xp);
        float G0 = m0 * m0, G1 = m1 * m1, G2 = m2 * m2, G3 = m3 * m3, G4 = m4 * m4;
        x[0] = __builtin_fmaf(lam, G1 - G0, x[0]);
        x[1] = __builtin_fmaf(lam, G2 - G1, x[1]);
        x[2] = __builtin_fmaf(lam, G3 - G2, x[2]);
        x[3] = __builtin_fmaf(lam, G4 - G3, x[3]);
        if (edgeBlk) {   // wave-uniform; skipped by 14/16 blocks
#pragma unroll
            for (int c = 0; c < 4; ++c) x[c] = laneIn ? x[c] : gxv;
        }
    };

    // Collect-then-store octet: 8 steps into 8 DISTINCT float4 register sets,
    // 8 distinct address regs, then 8 back-to-back stores. Register-reuse
    // distance for store data/addresses = one full octet (~900 cyc) >> the
    // ~250cyc store-data-read ack, so the compiler's WAR s_waitcnt never
    // stalls. (R17 at VGPR=20 recycled the same 4 store temps every step ->
    // one full store ack per step on the critical path = the 116 ns/step.)
    auto octet = [&](auto NQc) {
        constexpr int NQ = NQc.value;
        float4 sv[NQ];
#pragma unroll
        for (int q = 0; q < NQ; ++q) {
            do_step();
            sv[q] = make_float4(x[0] + 0.5f, x[1] + 0.5f, x[2] + 0.5f, x[3] + 0.5f);
        }
        char* a[NQ];
#pragma unroll
        for (int q = 0; q < NQ; ++q) a[q] = pstore + (size_t)q * incB;
#pragma unroll
        for (int q = 0; q < NQ; ++q)
            *reinterpret_cast<float4*>(a[q]) = sv[q];
        pstore += (size_t)NQ * incB;
    };

#pragma unroll 1
    for (int s = 0; s < kNS; ++s) {
        // ---- re-seed halo lanes from neighbors (state at time 64*s) ----
        if (s > 0) {
            const bool needL = (k > 0), needR = (k < 15);
            if (lane == 0) {   // lane-0-only poll; whole wave waits on branch
                const int* fL = flags + (p - 1) * kNS + s;
                const int* fR = flags + (p + 1) * kNS + s;
                int okL = needL ? 0 : 1, okR = needR ? 0 : 1;
                for (int it = 0; it < (1 << 22); ++it) {
                    if (!okL) okL = mall_loadi(fL);
                    if (!okR) okR = mall_loadi(fR);
                    if (okL && okR) break;
                    __builtin_amdgcn_s_sleep(1);
                }
            }
            asm volatile("" ::: "memory");   // keep data reads below the spin

            if (lane < 16) {
                if (needL) {  // left neighbor's cells 64..127
                    const int* hp = halo + ((size_t)((p - 1) * kNS + s)) * kChunk
                                  + 64 + 4 * lane;
#pragma unroll
                    for (int c = 0; c < 4; ++c) x[c] = mall_loadf(hp + c) - 0.5f;
                }  // k==0: lanes stay pinned
            } else if (lane >= 48) {
                if (needR) {  // right neighbor's cells 0..63
                    const int* hp = halo + ((size_t)((p + 1) * kNS + s)) * kChunk
                                  + 4 * (lane - 48);
#pragma unroll
                    for (int c = 0; c < 4; ++c) x[c] = mall_loadf(hp + c) - 0.5f;
                }  // k==15: lanes stay pinned
            }
            // lanes 16..47 keep their registers (own chunk, still valid)
        }

        // ---- steps: 8 octets (last superstep: 7 octets + 7) ----
        const int noct = (s == kNS - 1) ? 7 : 8;
#pragma unroll 1
        for (int g = 0; g < noct; ++g)
            octet(std::integral_constant<int, 8>{});
        if (s == kNS - 1)
            octet(std::integral_constant<int, 7>{});   // rows 505..511

        // ---- publish own chunk state (time 64*(s+1)) + flag, all relaxed ----
        if (s < kNS - 1) {
            if (writer) {
                int* hp = halo + ((size_t)(fbase + (s + 1))) * kChunk + 4 * (lane - 16);
#pragma unroll
                for (int c = 0; c < 4; ++c) mall_store(hp + c, x[c] + 0.5f);
            }
            // drain data exchs (vmcnt covers global atomics), then set flag
            asm volatile("s_waitcnt vmcnt(0)" ::: "memory");
            if (lane == 0)
                (void)__hip_atomic_exchange(flags + fbase + (s + 1), 1,
                                            __ATOMIC_RELAXED, __HIP_MEMORY_SCOPE_AGENT);
        }
    }
}

}  // namespace

extern "C" void kernel_launch(void* const* d_in, const int* in_sizes, int n_in,
                              void* d_out, int out_size, void* d_ws, size_t ws_size,
                              hipStream_t stream) {
    const float* xs  = (const float*)d_in[0];
    const float* ks  = (const float*)d_in[1];
    const int*   pm  = (const int*)d_in[2];
    const float* dxv = (const float*)d_in[3];
    const float* dtv = (const float*)d_in[4];
    // d_in[5] = t_coords: only carries the (NT, NX) shape; values unused.
    float* out = (float*)d_out;

    int* flags = (int*)d_ws;
    int* halo  = (int*)((char*)d_ws + kHaloOff);

    // Flags must be zeroed every call (d_ws is not re-poisoned between replays).
    hipMemsetAsync(flags, 0, kFlagsBytes, stream);

    hipLaunchKernelGGL(godunov_fused, dim3(kSolver), dim3(64), 0, stream,
                       xs, ks, pm, dxv, dtv, out, flags, halo);
}